// Round 9
// baseline (224.531 us; speedup 1.0000x reference)
//
#include <hip/hip_runtime.h>

#define N_NODES 100000
#define N_EDGES 20000
#define NNZ_C   600000
#define D 128

typedef short bf16x8 __attribute__((ext_vector_type(8)));
typedef float f32x4  __attribute__((ext_vector_type(4)));

__device__ __forceinline__ unsigned short f2bf(float f) {
    unsigned int u = __float_as_uint(f);
    u = (u + 0x7fffu + ((u >> 16) & 1u)) >> 16;   // RNE
    return (unsigned short)u;
}
__device__ __forceinline__ float bf2f(unsigned short h) {
    return __uint_as_float((unsigned int)h << 16);
}
// pack two fp32 -> two bf16 (truncation) in one v_perm_b32
__device__ __forceinline__ unsigned int pk_trunc(float lo, float hi) {
    return __builtin_amdgcn_perm(__float_as_uint(hi), __float_as_uint(lo),
                                 0x07060302);
}

// ---------------------------------------------------------------------------
// Math plan (linearity): out = (D^-1 H B^-1 H^T xb) @ cW + xb @ rW + (cb+rb)
//   1. fused_bin_conv : bucket COO + xb = bf16(x) + W^T bf16
//   2. edge_mean      : s_e = mean_{n in e} xb[n]
//   3. node_gemm      : z tile = mean_{e at n} s[e]; out = z@cW + xb@rW + b
// Claim-chain fix: bucket counters/storage sharded 16-way by (bid & 15) --
// same-shard claimants share an XCD, so base claims are L2-local and ~9 deep
// instead of 147-deep cross-XCD bounce chains (the measured 38-43 us).
// ---------------------------------------------------------------------------
#define CH 4096
#define NCHUNK 147            // ceil(600000/4096)
#define CONVB 256             // x->bf16 convert blocks (grid-stride)
#define WBLK 8                // W transpose blocks
#define NSH 16                // shards per bucket (bid & 15 -> one XCD each)
#define EBW 16                // edges per bucket
#define NBE 1250              // 20000/16 exact
#define ECAP_SH 96            // per-shard cap: mean 30, +12σ; 384B line-aligned
#define NBW 64                // nodes per bucket
#define NBN 1563              // ceil(100000/64)
#define NCAP_SH 64            // per-shard cap: mean 24, +8σ; 256B line-aligned
#define PADI 32               // ints per counter line (128 B)
#define GCUR_INTS ((NBE + NBN) * NSH * PADI)
#define TAGSH 21              // bucket tag shift; pk fits 21 bits
#define PKMASK 0x1FFFFF

#define GT 64
#define XPAD 136

// ---------------------------------------------------------------------------
// Kernel 1: blocks [0,147) bin the COO; [147,403) convert x->bf16;
// [403,411) transpose W -> bf16 [f][k].
// ---------------------------------------------------------------------------
__global__ __launch_bounds__(512) void fused_bin_conv(
    const float* __restrict__ x,
    const int* __restrict__ nidx, const int* __restrict__ eidx,
    const float* __restrict__ cW, const float* __restrict__ rW,
    unsigned short* __restrict__ xb,
    unsigned short* __restrict__ wtc, unsigned short* __restrict__ wtr,
    int* __restrict__ bucket_e, int* __restrict__ bucket_n,
    int* __restrict__ gcur_e, int* __restrict__ gcur_n) {
    __shared__ int srt[CH];
    __shared__ int cnt[NBN], lbase[NBN], gbase[NBN], cur[NBN];
    const int bid = blockIdx.x;
    const int tid = threadIdx.x;

    if (bid >= NCHUNK + CONVB) {
        // -------- W transpose role: 8 blocks x 4096 elements
        const int t0 = (bid - NCHUNK - CONVB) * 4096;
        for (int i = tid; i < 4096; i += 512) {
            const int t = t0 + i;
            const int m = t >> 14, idx = t & 16383;
            const int f = idx & 127, k = idx >> 7;
            const float* src = m ? rW : cW;
            unsigned short* dst = m ? wtr : wtc;
            dst[f * D + k] = f2bf(src[k * D + f]);
        }
        return;
    }
    if (bid >= NCHUNK) {
        // -------- convert role: xb = bf16(x), grid-stride over 8-elt groups
        const int total8 = N_NODES * D / 8;           // 1.6M
        for (int g = (bid - NCHUNK) * 512 + tid; g < total8;
             g += CONVB * 512) {
            const float4 a = *(const float4*)(x + (size_t)g * 8);
            const float4 c = *(const float4*)(x + (size_t)g * 8 + 4);
            uint4 v;
            v.x = pk_trunc(a.x, a.y);
            v.y = pk_trunc(a.z, a.w);
            v.z = pk_trunc(c.x, c.y);
            v.w = pk_trunc(c.z, c.w);
            *(uint4*)(xb + (size_t)g * 8) = v;
        }
        return;
    }

    // -------- bin role
    const int shard = bid & (NSH - 1);   // consecutive bids -> distinct XCDs
    const int j0 = bid * CH;
    const int jn = (j0 + CH < NNZ_C) ? CH : NNZ_C - j0;
#pragma unroll
    for (int s = 0; s < 2; ++s) {
        const int nb = s ? NBN : NBE;
        int* gc = s ? gcur_n : gcur_e;
        int* dst = s ? bucket_n : bucket_e;
        const int capsh = s ? NCAP_SH : ECAP_SH;
        for (int i = tid; i < nb; i += 512) cnt[i] = 0;
        __syncthreads();
        for (int i = tid; i < jn; i += 512) {
            const int id = s ? nidx[j0 + i] : eidx[j0 + i];
            atomicAdd(&cnt[s ? (id >> 6) : (id >> 4)], 1);
        }
        __syncthreads();
        // wave-0 scan: 25 bins/lane covers 1563
        if (tid < 64) {
            int loc[25];
            int ssum = 0;
            const int k0 = tid * 25;
#pragma unroll
            for (int k = 0; k < 25; ++k) {
                const int idx = k0 + k;
                loc[k] = ssum;
                if (idx < nb) ssum += cnt[idx];
            }
            int v = ssum;
#pragma unroll
            for (int off = 1; off < 64; off <<= 1) {
                const int t = __shfl_up(v, off);
                if (tid >= off) v += t;
            }
            const int base = v - ssum;
#pragma unroll
            for (int k = 0; k < 25; ++k) {
                const int idx = k0 + k;
                if (idx < nb) {
                    lbase[idx] = base + loc[k];
                    cur[idx] = base + loc[k];
                }
            }
        }
        __syncthreads();
        // per-bucket base claim on THIS BLOCK'S SHARD counter (XCD-local,
        // ~9-deep chain instead of 147-deep cross-XCD)
        for (int i = tid; i < nb; i += 512)
            gbase[i] = cnt[i] ? atomicAdd(&gc[(i * NSH + shard) * PADI], cnt[i]) : 0;
        __syncthreads();
        // LDS bin-sort scatter (COO re-read, L2-hot); tag rides bits 21..31
        for (int i = tid; i < jn; i += 512) {
            const int e = eidx[j0 + i], n = nidx[j0 + i];
            const int b = s ? (n >> 6) : (e >> 4);
            const unsigned pk = s ? (unsigned)(((n & 63) << 15) | e)
                                  : (unsigned)(((e & 15) << 17) | n);
            const int pos = atomicAdd(&cur[b], 1);
            srt[pos] = (int)(pk | ((unsigned)b << TAGSH));
        }
        __syncthreads();
        // ordered write-out: contiguous run per (bucket, shard) segment
        for (int i = tid; i < jn; i += 512) {
            const unsigned v = (unsigned)srt[i];
            const int b = (int)(v >> TAGSH);
            const int o2 = gbase[b] + (i - lbase[b]);
            if (o2 < capsh)
                dst[(b * NSH + shard) * capsh + o2] = (int)(v & PKMASK);
        }
        __syncthreads();
    }
}

// ---------------------------------------------------------------------------
// Kernel 2: edge mean. Block = 16-edge bucket (16 shard segments), 256 thr.
// Counting-sort in LDS over the shards, then 16 groups x 1 edge gather.
// ---------------------------------------------------------------------------
__global__ __launch_bounds__(256) void edge_mean(
    const int* __restrict__ bucket_e, const int* __restrict__ gcur_e,
    const unsigned short* __restrict__ xb, unsigned short* __restrict__ sb) {
    __shared__ int srt[NSH * ECAP_SH];
    __shared__ int cnt[EBW + 1];
    __shared__ int cur[EBW];
    const int tid = threadIdx.x;
    const int b = blockIdx.x;
    int Wsh[NSH];
#pragma unroll
    for (int sh = 0; sh < NSH; ++sh) {
        int c = gcur_e[(b * NSH + sh) * PADI];
        Wsh[sh] = (c < ECAP_SH) ? c : ECAP_SH;
    }
    if (tid <= EBW) cnt[tid] = 0;
    __syncthreads();
#pragma unroll
    for (int sh = 0; sh < NSH; ++sh) {
        const int* seg = bucket_e + (b * NSH + sh) * ECAP_SH;
        for (int i = tid; i < Wsh[sh]; i += 256)
            atomicAdd(&cnt[seg[i] >> 17], 1);
    }
    __syncthreads();
    if (tid < EBW) {        // 16-lane exclusive scan
        const int c = cnt[tid];
        int v = c;
#pragma unroll
        for (int off = 1; off < EBW; off <<= 1) {
            const int t = __shfl_up(v, off);
            if (tid >= off) v += t;
        }
        cnt[tid] = v - c;
        cur[tid] = v - c;
        if (tid == EBW - 1) cnt[EBW] = v;
    }
    __syncthreads();
#pragma unroll
    for (int sh = 0; sh < NSH; ++sh) {
        const int* seg = bucket_e + (b * NSH + sh) * ECAP_SH;
        for (int i = tid; i < Wsh[sh]; i += 256) {
            const int p = seg[i];
            const int pos = atomicAdd(&cur[p >> 17], 1);
            srt[pos] = p & 0x1FFFF;
        }
    }
    __syncthreads();

    const int g = tid >> 4;       // 16 groups, 1 edge each
    const int l = tid & 15;       // lane = 8 cols (16B)
    const int beg = cnt[g], end = cnt[g + 1];
    float acc[8] = {};
    int j = beg;
    for (; j + 8 <= end; j += 8) {
        bf16x8 p[8];
#pragma unroll
        for (int q = 0; q < 8; ++q)
            p[q] = *(const bf16x8*)(xb + (size_t)srt[j + q] * D + l * 8);
#pragma unroll
        for (int i = 0; i < 8; ++i) {
            float t0 = bf2f((unsigned short)p[0][i]) + bf2f((unsigned short)p[1][i]);
            float t1 = bf2f((unsigned short)p[2][i]) + bf2f((unsigned short)p[3][i]);
            float t2 = bf2f((unsigned short)p[4][i]) + bf2f((unsigned short)p[5][i]);
            float t3 = bf2f((unsigned short)p[6][i]) + bf2f((unsigned short)p[7][i]);
            acc[i] += (t0 + t1) + (t2 + t3);
        }
    }
    for (; j + 4 <= end; j += 4) {
        const int n0 = srt[j], n1 = srt[j + 1];
        const int n2 = srt[j + 2], n3 = srt[j + 3];
        const bf16x8 p0 = *(const bf16x8*)(xb + (size_t)n0 * D + l * 8);
        const bf16x8 p1 = *(const bf16x8*)(xb + (size_t)n1 * D + l * 8);
        const bf16x8 p2 = *(const bf16x8*)(xb + (size_t)n2 * D + l * 8);
        const bf16x8 p3 = *(const bf16x8*)(xb + (size_t)n3 * D + l * 8);
#pragma unroll
        for (int i = 0; i < 8; ++i)
            acc[i] += (bf2f((unsigned short)p0[i]) + bf2f((unsigned short)p1[i]))
                    + (bf2f((unsigned short)p2[i]) + bf2f((unsigned short)p3[i]));
    }
    for (; j < end; ++j) {
        const bf16x8 p = *(const bf16x8*)(xb + (size_t)srt[j] * D + l * 8);
#pragma unroll
        for (int i = 0; i < 8; ++i) acc[i] += bf2f((unsigned short)p[i]);
    }
    const int deg = end - beg;
    const float inv = deg ? 1.f / (float)deg : 0.f;
    bf16x8 o;
#pragma unroll
    for (int i = 0; i < 8; ++i) o[i] = (short)f2bf(acc[i] * inv);
    *(bf16x8*)(sb + (size_t)(b * EBW + g) * D + l * 8) = o;   // 1250*16 = 20000
}

// ---------------------------------------------------------------------------
// Kernel 3: node mean + dual GEMM. Block = 64-node bucket (16 segments) =
// one 64-row tile. Sort, gather s -> z tile, stage xb tile, dual MFMA, out.
// ---------------------------------------------------------------------------
__global__ __launch_bounds__(512, 4) void node_gemm(
    const int* __restrict__ bucket_n, const int* __restrict__ gcur_n,
    const unsigned short* __restrict__ sb, const unsigned short* __restrict__ xb,
    const unsigned short* __restrict__ wtc, const unsigned short* __restrict__ wtr,
    const float* __restrict__ cbias, const float* __restrict__ rbias,
    float* __restrict__ out) {
    __shared__ int srt[NSH * NCAP_SH];
    __shared__ int cnt[NBW + 1];
    __shared__ int cur[NBW];
    __shared__ unsigned short zs[NBW * XPAD];   // 64-row z tile (17.4 KB)
    __shared__ unsigned short xs[GT * XPAD];    // 64-row x tile (17.4 KB)
    const int tid = threadIdx.x;
    const int b = blockIdx.x;

    int Wsh[NSH];
#pragma unroll
    for (int sh = 0; sh < NSH; ++sh) {
        int c = gcur_n[(b * NSH + sh) * PADI];
        Wsh[sh] = (c < NCAP_SH) ? c : NCAP_SH;
    }
    if (tid <= NBW) cnt[tid] = 0;
    __syncthreads();
#pragma unroll
    for (int sh = 0; sh < NSH; ++sh) {
        const int* seg = bucket_n + (b * NSH + sh) * NCAP_SH;
        for (int i = tid; i < Wsh[sh]; i += 512)
            atomicAdd(&cnt[seg[i] >> 15], 1);
    }
    __syncthreads();
    if (tid < 64) {          // wave-0 scan, 1 bin/lane
        const int c = cnt[tid];
        int v = c;
#pragma unroll
        for (int off = 1; off < 64; off <<= 1) {
            const int t = __shfl_up(v, off);
            if (tid >= off) v += t;
        }
        cnt[tid] = v - c;
        cur[tid] = v - c;
        if (tid == 63) cnt[NBW] = v;
    }
    __syncthreads();
#pragma unroll
    for (int sh = 0; sh < NSH; ++sh) {
        const int* seg = bucket_n + (b * NSH + sh) * NCAP_SH;
        for (int i = tid; i < Wsh[sh]; i += 512) {
            const int p = seg[i];
            const int pos = atomicAdd(&cur[p >> 15], 1);
            srt[pos] = p & 0x7FFF;
        }
    }
    __syncthreads();

    // ---- gather s rows -> z tile rows (bf16 mean; empty rows -> 0) ----
    {
        const int g = tid >> 4;       // 32 groups, 2 nodes each
        const int l = tid & 15;
#pragma unroll
        for (int u = 0; u < 2; ++u) {
            const int nl = g * 2 + u;
            const int beg = cnt[nl], end = cnt[nl + 1];
            float acc[8] = {};
            int j = beg;
            for (; j + 4 <= end; j += 4) {
                const int e0 = srt[j], e1 = srt[j + 1];
                const int e2 = srt[j + 2], e3 = srt[j + 3];
                const bf16x8 p0 = *(const bf16x8*)(sb + (size_t)e0 * D + l * 8);
                const bf16x8 p1 = *(const bf16x8*)(sb + (size_t)e1 * D + l * 8);
                const bf16x8 p2 = *(const bf16x8*)(sb + (size_t)e2 * D + l * 8);
                const bf16x8 p3 = *(const bf16x8*)(sb + (size_t)e3 * D + l * 8);
#pragma unroll
                for (int i = 0; i < 8; ++i)
                    acc[i] += (bf2f((unsigned short)p0[i]) + bf2f((unsigned short)p1[i]))
                            + (bf2f((unsigned short)p2[i]) + bf2f((unsigned short)p3[i]));
            }
            for (; j < end; ++j) {
                const bf16x8 p = *(const bf16x8*)(sb + (size_t)srt[j] * D + l * 8);
#pragma unroll
                for (int i = 0; i < 8; ++i) acc[i] += bf2f((unsigned short)p[i]);
            }
            const int deg = end - beg;
            const float inv = deg ? 1.f / (float)deg : 0.f;
            bf16x8 o;
#pragma unroll
            for (int i = 0; i < 8; ++i) o[i] = (short)f2bf(acc[i] * inv);
            *(bf16x8*)(zs + nl * XPAD + l * 8) = o;
        }
    }

    // ---- W fragments (bf16 [f][k], 16B vector loads) & bias ----
    const int w    = tid >> 6;
    const int lane = tid & 63;
    const int quad = lane >> 4;
    const int l16  = lane & 15;
    const int f0   = w * 16;
    const int f    = f0 + l16;
    bf16x8 Ac[4], Ar[4];
#pragma unroll
    for (int kc = 0; kc < 4; ++kc) {
        Ac[kc] = *(const bf16x8*)(wtc + (size_t)f * D + kc * 32 + quad * 8);
        Ar[kc] = *(const bf16x8*)(wtr + (size_t)f * D + kc * 32 + quad * 8);
    }
    const float4 cb4 = *(const float4*)(cbias + f0 + quad * 4);
    const float4 rb4 = *(const float4*)(rbias + f0 + quad * 4);
    const float4 bias = {cb4.x + rb4.x, cb4.y + rb4.y,
                         cb4.z + rb4.z, cb4.w + rb4.w};

    // ---- stage xb tile (contiguous rows), dual MFMA, write out ----
    {
        const int r0 = tid >> 3;
        const int qp = tid & 7;
        int n = b * NBW + r0;
        if (n >= N_NODES) n = N_NODES - 1;
        const uint4* sx = (const uint4*)(xb + (size_t)n * D + qp * 16);
        uint4* dx = (uint4*)(xs + r0 * XPAD + qp * 16);
        dx[0] = sx[0]; dx[1] = sx[1];
    }
    __syncthreads();
    f32x4 acc[4] = {};
#pragma unroll
    for (int g = 0; g < 4; ++g)
#pragma unroll
        for (int kc = 0; kc < 4; ++kc) {
            const int ro = (g * 16 + l16) * XPAD + kc * 32 + quad * 8;
            const bf16x8 Bz = *(const bf16x8*)(zs + ro);
            const bf16x8 Bx = *(const bf16x8*)(xs + ro);
            acc[g] = __builtin_amdgcn_mfma_f32_16x16x32_bf16(Ac[kc], Bz, acc[g], 0, 0, 0);
            acc[g] = __builtin_amdgcn_mfma_f32_16x16x32_bf16(Ar[kc], Bx, acc[g], 0, 0, 0);
        }
#pragma unroll
    for (int g = 0; g < 4; ++g) {
        const int n = b * NBW + g * 16 + l16;
        if (n >= N_NODES) continue;
        float4 o;
        o.x = acc[g][0] + bias.x;
        o.y = acc[g][1] + bias.y;
        o.z = acc[g][2] + bias.z;
        o.w = acc[g][3] + bias.w;
        *(float4*)(out + (size_t)n * D + f0 + quad * 4) = o;
    }
}

// ---------------------------------------------------------------------------
extern "C" void kernel_launch(void* const* d_in, const int* in_sizes, int n_in,
                              void* d_out, int out_size, void* d_ws,
                              size_t ws_size, hipStream_t stream) {
    const float* x  = (const float*)d_in[0];
    const int* nidx = (const int*)d_in[1];
    const int* eidx = (const int*)d_in[2];
    const float* cW = (const float*)d_in[3];
    const float* cb = (const float*)d_in[4];
    const float* rW = (const float*)d_in[5];
    const float* rb = (const float*)d_in[6];
    float* out = (float*)d_out;

    char* ws = (char*)d_ws;
    size_t off = 0;
    auto alloc = [&](size_t bytes) {
        size_t o = off;
        off += (bytes + 255) & ~(size_t)255;
        return o;
    };
    unsigned short* xb  = (unsigned short*)(ws + alloc((size_t)N_NODES * D * 2));
    unsigned short* sb  = (unsigned short*)(ws + alloc((size_t)N_EDGES * D * 2));
    unsigned short* wtc = (unsigned short*)(ws + alloc((size_t)D * D * 2));
    unsigned short* wtr = (unsigned short*)(ws + alloc((size_t)D * D * 2));
    int* bucket_e = (int*)(ws + alloc((size_t)NBE * NSH * ECAP_SH * 4));
    int* bucket_n = (int*)(ws + alloc((size_t)NBN * NSH * NCAP_SH * 4));
    int* gcur     = (int*)(ws + alloc((size_t)GCUR_INTS * 4));
    int* gcur_e = gcur;
    int* gcur_n = gcur + NBE * NSH * PADI;

    hipMemsetAsync(gcur, 0, (size_t)GCUR_INTS * 4, stream);

    fused_bin_conv<<<NCHUNK + CONVB + WBLK, 512, 0, stream>>>(
        x, nidx, eidx, cW, rW, xb, wtc, wtr,
        bucket_e, bucket_n, gcur_e, gcur_n);

    edge_mean<<<NBE, 256, 0, stream>>>(bucket_e, gcur_e, xb, sb);
    node_gemm<<<NBN, 512, 0, stream>>>(bucket_n, gcur_n, sb, xb,
                                       wtc, wtr, cb, rb, out);
}

// Round 10
// 207.064 us; speedup vs baseline: 1.0844x; 1.0844x over previous
//
#include <hip/hip_runtime.h>

#define N_NODES 100000
#define N_EDGES 20000
#define NNZ_C   600000
#define D 128

typedef short bf16x8 __attribute__((ext_vector_type(8)));
typedef float f32x4  __attribute__((ext_vector_type(4)));

__device__ __forceinline__ unsigned short f2bf(float f) {
    unsigned int u = __float_as_uint(f);
    u = (u + 0x7fffu + ((u >> 16) & 1u)) >> 16;   // RNE
    return (unsigned short)u;
}
__device__ __forceinline__ float bf2f(unsigned short h) {
    return __uint_as_float((unsigned int)h << 16);
}
// pack two fp32 -> two bf16 (truncation) in one v_perm_b32
__device__ __forceinline__ unsigned int pk_trunc(float lo, float hi) {
    return __builtin_amdgcn_perm(__float_as_uint(hi), __float_as_uint(lo),
                                 0x07060302);
}

// ---------------------------------------------------------------------------
// Math plan (linearity): out = (D^-1 H B^-1 H^T xb) @ cW + xb @ rW + (cb+rb)
//   1. fused_bin_conv : bucket COO + xb = bf16(x) + W^T bf16
//   2. edge_mean      : s_e = mean_{n in e} xb[n]
//   3. node_gemm      : z tile = mean_{e at n} s[e]; out = z@cW + xb@rW + b
// Producer: 16-way XCD-sharded claim counters (r9, fixed the claim chains).
// Consumer fix (r10): read the 16 contiguous shard segments LINEARLY with
// all threads predicated (off < wsh[sh]) -- r9's per-segment loops left
// ~95% of lanes idle across 32 serial micro-loops.
// ---------------------------------------------------------------------------
#define CH 4096
#define NCHUNK 147            // ceil(600000/4096)
#define CONVB 256             // x->bf16 convert blocks (grid-stride)
#define WBLK 8                // W transpose blocks
#define NSH 16                // shards per bucket (bid & 15 -> one XCD each)
#define EBW 16                // edges per bucket
#define NBE 1250              // 20000/16 exact
#define ECAP_SH 96            // per-shard cap: mean 30, +12σ; 384B aligned
#define ESEG (NSH * ECAP_SH)  // 1536 padded entries per bucket
#define NBW 64                // nodes per bucket
#define NBN 1563              // ceil(100000/64)
#define NCAP_SH 64            // per-shard cap: mean 24, +8σ; 256B aligned
#define NSEG (NSH * NCAP_SH)  // 1024 padded entries per bucket
#define PADI 32               // ints per counter line (128 B)
#define GCUR_INTS ((NBE + NBN) * NSH * PADI)
#define TAGSH 21              // bucket tag shift; pk fits 21 bits
#define PKMASK 0x1FFFFF

#define GT 64
#define XPAD 136

// ---------------------------------------------------------------------------
// Kernel 1: blocks [0,147) bin the COO; [147,403) convert x->bf16;
// [403,411) transpose W -> bf16 [f][k].  (unchanged from r9)
// ---------------------------------------------------------------------------
__global__ __launch_bounds__(512) void fused_bin_conv(
    const float* __restrict__ x,
    const int* __restrict__ nidx, const int* __restrict__ eidx,
    const float* __restrict__ cW, const float* __restrict__ rW,
    unsigned short* __restrict__ xb,
    unsigned short* __restrict__ wtc, unsigned short* __restrict__ wtr,
    int* __restrict__ bucket_e, int* __restrict__ bucket_n,
    int* __restrict__ gcur_e, int* __restrict__ gcur_n) {
    __shared__ int srt[CH];
    __shared__ int cnt[NBN], lbase[NBN], gbase[NBN], cur[NBN];
    const int bid = blockIdx.x;
    const int tid = threadIdx.x;

    if (bid >= NCHUNK + CONVB) {
        // -------- W transpose role: 8 blocks x 4096 elements
        const int t0 = (bid - NCHUNK - CONVB) * 4096;
        for (int i = tid; i < 4096; i += 512) {
            const int t = t0 + i;
            const int m = t >> 14, idx = t & 16383;
            const int f = idx & 127, k = idx >> 7;
            const float* src = m ? rW : cW;
            unsigned short* dst = m ? wtr : wtc;
            dst[f * D + k] = f2bf(src[k * D + f]);
        }
        return;
    }
    if (bid >= NCHUNK) {
        // -------- convert role: xb = bf16(x), grid-stride over 8-elt groups
        const int total8 = N_NODES * D / 8;           // 1.6M
        for (int g = (bid - NCHUNK) * 512 + tid; g < total8;
             g += CONVB * 512) {
            const float4 a = *(const float4*)(x + (size_t)g * 8);
            const float4 c = *(const float4*)(x + (size_t)g * 8 + 4);
            uint4 v;
            v.x = pk_trunc(a.x, a.y);
            v.y = pk_trunc(a.z, a.w);
            v.z = pk_trunc(c.x, c.y);
            v.w = pk_trunc(c.z, c.w);
            *(uint4*)(xb + (size_t)g * 8) = v;
        }
        return;
    }

    // -------- bin role
    const int shard = bid & (NSH - 1);   // consecutive bids -> distinct XCDs
    const int j0 = bid * CH;
    const int jn = (j0 + CH < NNZ_C) ? CH : NNZ_C - j0;
#pragma unroll
    for (int s = 0; s < 2; ++s) {
        const int nb = s ? NBN : NBE;
        int* gc = s ? gcur_n : gcur_e;
        int* dst = s ? bucket_n : bucket_e;
        const int capsh = s ? NCAP_SH : ECAP_SH;
        for (int i = tid; i < nb; i += 512) cnt[i] = 0;
        __syncthreads();
        for (int i = tid; i < jn; i += 512) {
            const int id = s ? nidx[j0 + i] : eidx[j0 + i];
            atomicAdd(&cnt[s ? (id >> 6) : (id >> 4)], 1);
        }
        __syncthreads();
        // wave-0 scan: 25 bins/lane covers 1563
        if (tid < 64) {
            int loc[25];
            int ssum = 0;
            const int k0 = tid * 25;
#pragma unroll
            for (int k = 0; k < 25; ++k) {
                const int idx = k0 + k;
                loc[k] = ssum;
                if (idx < nb) ssum += cnt[idx];
            }
            int v = ssum;
#pragma unroll
            for (int off = 1; off < 64; off <<= 1) {
                const int t = __shfl_up(v, off);
                if (tid >= off) v += t;
            }
            const int base = v - ssum;
#pragma unroll
            for (int k = 0; k < 25; ++k) {
                const int idx = k0 + k;
                if (idx < nb) {
                    lbase[idx] = base + loc[k];
                    cur[idx] = base + loc[k];
                }
            }
        }
        __syncthreads();
        // per-bucket base claim on THIS BLOCK'S SHARD counter (XCD-local)
        for (int i = tid; i < nb; i += 512)
            gbase[i] = cnt[i] ? atomicAdd(&gc[(i * NSH + shard) * PADI], cnt[i]) : 0;
        __syncthreads();
        // LDS bin-sort scatter (COO re-read, L2-hot); tag rides bits 21..31
        for (int i = tid; i < jn; i += 512) {
            const int e = eidx[j0 + i], n = nidx[j0 + i];
            const int b = s ? (n >> 6) : (e >> 4);
            const unsigned pk = s ? (unsigned)(((n & 63) << 15) | e)
                                  : (unsigned)(((e & 15) << 17) | n);
            const int pos = atomicAdd(&cur[b], 1);
            srt[pos] = (int)(pk | ((unsigned)b << TAGSH));
        }
        __syncthreads();
        // ordered write-out: contiguous run per (bucket, shard) segment
        for (int i = tid; i < jn; i += 512) {
            const unsigned v = (unsigned)srt[i];
            const int b = (int)(v >> TAGSH);
            const int o2 = gbase[b] + (i - lbase[b]);
            if (o2 < capsh)
                dst[(b * NSH + shard) * capsh + o2] = (int)(v & PKMASK);
        }
        __syncthreads();
    }
}

// ---------------------------------------------------------------------------
// Kernel 2: edge mean. Block = 16-edge bucket (16 contiguous shard segments),
// 256 threads. LINEAR predicated read over the padded range (all lanes
// active, coalesced), LDS counting-sort, 16 groups x 1 edge gather.
// ---------------------------------------------------------------------------
__global__ __launch_bounds__(256) void edge_mean(
    const int* __restrict__ bucket_e, const int* __restrict__ gcur_e,
    const unsigned short* __restrict__ xb, unsigned short* __restrict__ sb) {
    __shared__ int srt[ESEG];
    __shared__ int cnt[EBW + 1];
    __shared__ int cur[EBW];
    __shared__ int wsh[NSH];
    const int tid = threadIdx.x;
    const int b = blockIdx.x;
    if (tid < NSH) {
        int c = gcur_e[(b * NSH + tid) * PADI];
        wsh[tid] = (c < ECAP_SH) ? c : ECAP_SH;
    }
    if (tid <= EBW) cnt[tid] = 0;
    __syncthreads();
    const int* seg0 = bucket_e + (size_t)b * ESEG;
    for (int i = tid; i < ESEG; i += 256) {
        const int sh = i / ECAP_SH;           // const-div (mul-shift)
        const int off = i - sh * ECAP_SH;
        if (off < wsh[sh]) atomicAdd(&cnt[seg0[i] >> 17], 1);
    }
    __syncthreads();
    if (tid < EBW) {        // 16-lane exclusive scan
        const int c = cnt[tid];
        int v = c;
#pragma unroll
        for (int off = 1; off < EBW; off <<= 1) {
            const int t = __shfl_up(v, off);
            if (tid >= off) v += t;
        }
        cnt[tid] = v - c;
        cur[tid] = v - c;
        if (tid == EBW - 1) cnt[EBW] = v;
    }
    __syncthreads();
    for (int i = tid; i < ESEG; i += 256) {
        const int sh = i / ECAP_SH;
        const int off = i - sh * ECAP_SH;
        if (off < wsh[sh]) {
            const int p = seg0[i];
            const int pos = atomicAdd(&cur[p >> 17], 1);
            srt[pos] = p & 0x1FFFF;
        }
    }
    __syncthreads();

    const int g = tid >> 4;       // 16 groups, 1 edge each
    const int l = tid & 15;       // lane = 8 cols (16B)
    const int beg = cnt[g], end = cnt[g + 1];
    float acc[8] = {};
    int j = beg;
    for (; j + 8 <= end; j += 8) {
        bf16x8 p[8];
#pragma unroll
        for (int q = 0; q < 8; ++q)
            p[q] = *(const bf16x8*)(xb + (size_t)srt[j + q] * D + l * 8);
#pragma unroll
        for (int i = 0; i < 8; ++i) {
            float t0 = bf2f((unsigned short)p[0][i]) + bf2f((unsigned short)p[1][i]);
            float t1 = bf2f((unsigned short)p[2][i]) + bf2f((unsigned short)p[3][i]);
            float t2 = bf2f((unsigned short)p[4][i]) + bf2f((unsigned short)p[5][i]);
            float t3 = bf2f((unsigned short)p[6][i]) + bf2f((unsigned short)p[7][i]);
            acc[i] += (t0 + t1) + (t2 + t3);
        }
    }
    for (; j + 4 <= end; j += 4) {
        const int n0 = srt[j], n1 = srt[j + 1];
        const int n2 = srt[j + 2], n3 = srt[j + 3];
        const bf16x8 p0 = *(const bf16x8*)(xb + (size_t)n0 * D + l * 8);
        const bf16x8 p1 = *(const bf16x8*)(xb + (size_t)n1 * D + l * 8);
        const bf16x8 p2 = *(const bf16x8*)(xb + (size_t)n2 * D + l * 8);
        const bf16x8 p3 = *(const bf16x8*)(xb + (size_t)n3 * D + l * 8);
#pragma unroll
        for (int i = 0; i < 8; ++i)
            acc[i] += (bf2f((unsigned short)p0[i]) + bf2f((unsigned short)p1[i]))
                    + (bf2f((unsigned short)p2[i]) + bf2f((unsigned short)p3[i]));
    }
    for (; j < end; ++j) {
        const bf16x8 p = *(const bf16x8*)(xb + (size_t)srt[j] * D + l * 8);
#pragma unroll
        for (int i = 0; i < 8; ++i) acc[i] += bf2f((unsigned short)p[i]);
    }
    const int deg = end - beg;
    const float inv = deg ? 1.f / (float)deg : 0.f;
    bf16x8 o;
#pragma unroll
    for (int i = 0; i < 8; ++i) o[i] = (short)f2bf(acc[i] * inv);
    *(bf16x8*)(sb + (size_t)(b * EBW + g) * D + l * 8) = o;   // 1250*16 = 20000
}

// ---------------------------------------------------------------------------
// Kernel 3: node mean + dual GEMM. Block = 64-node bucket (16 contiguous
// segments) = one 64-row tile. Linear predicated segment read, LDS sort,
// gather s -> z tile, dual MFMA, out. xs staging + W loads hoisted early.
// ---------------------------------------------------------------------------
__global__ __launch_bounds__(512, 4) void node_gemm(
    const int* __restrict__ bucket_n, const int* __restrict__ gcur_n,
    const unsigned short* __restrict__ sb, const unsigned short* __restrict__ xb,
    const unsigned short* __restrict__ wtc, const unsigned short* __restrict__ wtr,
    const float* __restrict__ cbias, const float* __restrict__ rbias,
    float* __restrict__ out) {
    __shared__ int srt[NSEG];
    __shared__ int cnt[NBW + 1];
    __shared__ int cur[NBW];
    __shared__ int wsh[NSH];
    __shared__ unsigned short zs[NBW * XPAD];   // 64-row z tile (17.4 KB)
    __shared__ unsigned short xs[GT * XPAD];    // 64-row x tile (17.4 KB)
    const int tid = threadIdx.x;
    const int b = blockIdx.x;

    if (tid < NSH) {
        int c = gcur_n[(b * NSH + tid) * PADI];
        wsh[tid] = (c < NCAP_SH) ? c : NCAP_SH;
    }
    if (tid <= NBW) cnt[tid] = 0;

    // ---- hoisted: stage xb tile (global loads issue under the sort) ----
    {
        const int r0 = tid >> 3;
        const int qp = tid & 7;
        int n = b * NBW + r0;
        if (n >= N_NODES) n = N_NODES - 1;
        const uint4* sx = (const uint4*)(xb + (size_t)n * D + qp * 16);
        uint4* dx = (uint4*)(xs + r0 * XPAD + qp * 16);
        dx[0] = sx[0]; dx[1] = sx[1];
    }
    // ---- hoisted: W fragments (bf16 [f][k]) & bias ----
    const int w    = tid >> 6;
    const int lane = tid & 63;
    const int quad = lane >> 4;
    const int l16  = lane & 15;
    const int f0   = w * 16;
    const int f    = f0 + l16;
    bf16x8 Ac[4], Ar[4];
#pragma unroll
    for (int kc = 0; kc < 4; ++kc) {
        Ac[kc] = *(const bf16x8*)(wtc + (size_t)f * D + kc * 32 + quad * 8);
        Ar[kc] = *(const bf16x8*)(wtr + (size_t)f * D + kc * 32 + quad * 8);
    }
    const float4 cb4 = *(const float4*)(cbias + f0 + quad * 4);
    const float4 rb4 = *(const float4*)(rbias + f0 + quad * 4);
    const float4 bias = {cb4.x + rb4.x, cb4.y + rb4.y,
                         cb4.z + rb4.z, cb4.w + rb4.w};
    __syncthreads();

    // ---- counting sort via linear predicated segment reads ----
    const int* seg0 = bucket_n + (size_t)b * NSEG;
    for (int i = tid; i < NSEG; i += 512) {
        const int sh = i >> 6;                 // NCAP_SH = 64
        const int off = i & (NCAP_SH - 1);
        if (off < wsh[sh]) atomicAdd(&cnt[seg0[i] >> 15], 1);
    }
    __syncthreads();
    if (tid < 64) {          // wave-0 scan, 1 bin/lane
        const int c = cnt[tid];
        int v = c;
#pragma unroll
        for (int off = 1; off < 64; off <<= 1) {
            const int t = __shfl_up(v, off);
            if (tid >= off) v += t;
        }
        cnt[tid] = v - c;
        cur[tid] = v - c;
        if (tid == 63) cnt[NBW] = v;
    }
    __syncthreads();
    for (int i = tid; i < NSEG; i += 512) {
        const int sh = i >> 6;
        const int off = i & (NCAP_SH - 1);
        if (off < wsh[sh]) {
            const int p = seg0[i];
            const int pos = atomicAdd(&cur[p >> 15], 1);
            srt[pos] = p & 0x7FFF;
        }
    }
    __syncthreads();

    // ---- gather s rows -> z tile rows (bf16 mean; empty rows -> 0) ----
    {
        const int g = tid >> 4;       // 32 groups, 2 nodes each
        const int l = tid & 15;
#pragma unroll
        for (int u = 0; u < 2; ++u) {
            const int nl = g * 2 + u;
            const int beg = cnt[nl], end = cnt[nl + 1];
            float acc[8] = {};
            int j = beg;
            for (; j + 4 <= end; j += 4) {
                const int e0 = srt[j], e1 = srt[j + 1];
                const int e2 = srt[j + 2], e3 = srt[j + 3];
                const bf16x8 p0 = *(const bf16x8*)(sb + (size_t)e0 * D + l * 8);
                const bf16x8 p1 = *(const bf16x8*)(sb + (size_t)e1 * D + l * 8);
                const bf16x8 p2 = *(const bf16x8*)(sb + (size_t)e2 * D + l * 8);
                const bf16x8 p3 = *(const bf16x8*)(sb + (size_t)e3 * D + l * 8);
#pragma unroll
                for (int i = 0; i < 8; ++i)
                    acc[i] += (bf2f((unsigned short)p0[i]) + bf2f((unsigned short)p1[i]))
                            + (bf2f((unsigned short)p2[i]) + bf2f((unsigned short)p3[i]));
            }
            for (; j < end; ++j) {
                const bf16x8 p = *(const bf16x8*)(sb + (size_t)srt[j] * D + l * 8);
#pragma unroll
                for (int i = 0; i < 8; ++i) acc[i] += bf2f((unsigned short)p[i]);
            }
            const int deg = end - beg;
            const float inv = deg ? 1.f / (float)deg : 0.f;
            bf16x8 o;
#pragma unroll
            for (int i = 0; i < 8; ++i) o[i] = (short)f2bf(acc[i] * inv);
            *(bf16x8*)(zs + nl * XPAD + l * 8) = o;
        }
    }
    __syncthreads();

    // ---- dual MFMA over z (conv path) and x (residual path), write out ----
    f32x4 acc[4] = {};
#pragma unroll
    for (int g = 0; g < 4; ++g)
#pragma unroll
        for (int kc = 0; kc < 4; ++kc) {
            const int ro = (g * 16 + l16) * XPAD + kc * 32 + quad * 8;
            const bf16x8 Bz = *(const bf16x8*)(zs + ro);
            const bf16x8 Bx = *(const bf16x8*)(xs + ro);
            acc[g] = __builtin_amdgcn_mfma_f32_16x16x32_bf16(Ac[kc], Bz, acc[g], 0, 0, 0);
            acc[g] = __builtin_amdgcn_mfma_f32_16x16x32_bf16(Ar[kc], Bx, acc[g], 0, 0, 0);
        }
#pragma unroll
    for (int g = 0; g < 4; ++g) {
        const int n = b * NBW + g * 16 + l16;
        if (n >= N_NODES) continue;
        float4 o;
        o.x = acc[g][0] + bias.x;
        o.y = acc[g][1] + bias.y;
        o.z = acc[g][2] + bias.z;
        o.w = acc[g][3] + bias.w;
        *(float4*)(out + (size_t)n * D + f0 + quad * 4) = o;
    }
}

// ---------------------------------------------------------------------------
extern "C" void kernel_launch(void* const* d_in, const int* in_sizes, int n_in,
                              void* d_out, int out_size, void* d_ws,
                              size_t ws_size, hipStream_t stream) {
    const float* x  = (const float*)d_in[0];
    const int* nidx = (const int*)d_in[1];
    const int* eidx = (const int*)d_in[2];
    const float* cW = (const float*)d_in[3];
    const float* cb = (const float*)d_in[4];
    const float* rW = (const float*)d_in[5];
    const float* rb = (const float*)d_in[6];
    float* out = (float*)d_out;

    char* ws = (char*)d_ws;
    size_t off = 0;
    auto alloc = [&](size_t bytes) {
        size_t o = off;
        off += (bytes + 255) & ~(size_t)255;
        return o;
    };
    unsigned short* xb  = (unsigned short*)(ws + alloc((size_t)N_NODES * D * 2));
    unsigned short* sb  = (unsigned short*)(ws + alloc((size_t)N_EDGES * D * 2));
    unsigned short* wtc = (unsigned short*)(ws + alloc((size_t)D * D * 2));
    unsigned short* wtr = (unsigned short*)(ws + alloc((size_t)D * D * 2));
    int* bucket_e = (int*)(ws + alloc((size_t)NBE * ESEG * 4));
    int* bucket_n = (int*)(ws + alloc((size_t)NBN * NSEG * 4));
    int* gcur     = (int*)(ws + alloc((size_t)GCUR_INTS * 4));
    int* gcur_e = gcur;
    int* gcur_n = gcur + NBE * NSH * PADI;

    hipMemsetAsync(gcur, 0, (size_t)GCUR_INTS * 4, stream);

    fused_bin_conv<<<NCHUNK + CONVB + WBLK, 512, 0, stream>>>(
        x, nidx, eidx, cW, rW, xb, wtc, wtr,
        bucket_e, bucket_n, gcur_e, gcur_n);

    edge_mean<<<NBE, 256, 0, stream>>>(bucket_e, gcur_e, xb, sb);
    node_gemm<<<NBN, 512, 0, stream>>>(bucket_n, gcur_n, sb, xb,
                                       wtc, wtr, cb, rb, out);
}